// Round 3
// baseline (59.073 us; speedup 1.0000x reference)
//
#include <hip/hip_runtime.h>
#include <hip/hip_bf16.h>

// Q8_0-style fused dequant + linear: y[32,11008] = x[32,4096] @ W^T + bias
// W[o,i] = (qweight[o,i] - 127) * scales[o, i/32]
//
// Round 3: LDS-free, barrier-free MFMA streaming kernel.
// Each wave owns a 16-o x 32-b output tile and a K-split of 512.
// B-fragment (weights) loaded straight from global as 2x dwordx4 per lane
// (16 rows x 128 contiguous bytes per k-step), dequantized in registers.
// A-fragment (x, pre-converted to bf16 in d_ws) read from global (L2-resident).
// One MFMA k=32 == one Q8_0 scale block, so one scale per lane per step.
// K-split partials combined with f32 atomicAdd into bias-pre-initialized out.

#define O_DIM  11008
#define I_DIM  4096
#define NB     128           // scale blocks per o-row
#define B_DIM  32
#define NSPLIT 8
#define KT     (I_DIM / NSPLIT)  // 512
#define NSTEP  (KT / 32)         // 16

typedef __attribute__((ext_vector_type(8))) short bf16x8;
typedef __attribute__((ext_vector_type(4))) float f32x4;

static __device__ __forceinline__ unsigned short f2bf(float f) {
    return __builtin_bit_cast(unsigned short, __float2bfloat16(f));
}

// out = bias (row broadcast); x -> bf16 into d_ws.
__global__ __launch_bounds__(256) void init_kernel(const float* __restrict__ x,
                                                   const float* __restrict__ bias,
                                                   float* __restrict__ out,
                                                   unsigned short* __restrict__ xbf) {
    const int gid = blockIdx.x * 256 + threadIdx.x;
    const int b = gid / O_DIM;
    const int o = gid - b * O_DIM;
    out[gid] = bias[o];
    if (gid < (B_DIM * I_DIM) / 4) {
        const float4 v = reinterpret_cast<const float4*>(x)[gid];
        ushort4 u;
        u.x = f2bf(v.x); u.y = f2bf(v.y); u.z = f2bf(v.z); u.w = f2bf(v.w);
        reinterpret_cast<ushort4*>(xbf)[gid] = u;
    }
}

static __device__ __forceinline__ bf16x8 dequant8(const int4 qa, const int4 qb,
                                                  const float s) {
    const float c = -127.0f * s;
    bf16x8 v;
    v[0] = (short)f2bf(fmaf((float)qa.x, s, c));
    v[1] = (short)f2bf(fmaf((float)qa.y, s, c));
    v[2] = (short)f2bf(fmaf((float)qa.z, s, c));
    v[3] = (short)f2bf(fmaf((float)qa.w, s, c));
    v[4] = (short)f2bf(fmaf((float)qb.x, s, c));
    v[5] = (short)f2bf(fmaf((float)qb.y, s, c));
    v[6] = (short)f2bf(fmaf((float)qb.z, s, c));
    v[7] = (short)f2bf(fmaf((float)qb.w, s, c));
    return v;
}

__global__ __launch_bounds__(256) void gemm_stream_kernel(const unsigned short* __restrict__ xbf,
                                                          const int*   __restrict__ qw,
                                                          const float* __restrict__ scales,
                                                          float*       __restrict__ out) {
    const int t    = threadIdx.x;
    const int wav  = t >> 6;
    const int lan  = t & 63;
    const int lrow = lan & 15;     // fragment row
    const int lq   = lan >> 4;     // lane quarter -> k sub-offset

    const int o_base = blockIdx.x * 64 + wav * 16;  // wave's o-slice
    const int k_base = blockIdx.y * KT;             // K-split
    const int o_row  = o_base + lrow;

    const int*            __restrict__ wq = qw  + o_row * I_DIM + k_base + lq * 8;
    const unsigned short* __restrict__ xa = xbf + lrow * I_DIM + k_base + lq * 8;

    // preload this row's 16 scales for the K-split (one per k-step of 32)
    float sc[NSTEP];
    {
        const float4* sp = reinterpret_cast<const float4*>(&scales[o_row * NB + (k_base >> 5)]);
#pragma unroll
        for (int j = 0; j < 4; ++j) {
            const float4 v = sp[j];
            sc[4 * j + 0] = v.x; sc[4 * j + 1] = v.y;
            sc[4 * j + 2] = v.z; sc[4 * j + 3] = v.w;
        }
    }

    f32x4 acc0 = {0.f, 0.f, 0.f, 0.f};   // m rows 0..15
    f32x4 acc1 = {0.f, 0.f, 0.f, 0.f};   // m rows 16..31

    // 2-deep register pipeline, fully unrolled (all indices static)
    int4   qa = *reinterpret_cast<const int4*>(wq);
    int4   qb = *reinterpret_cast<const int4*>(wq + 4);
    bf16x8 a0 = *reinterpret_cast<const bf16x8*>(xa);
    bf16x8 a1 = *reinterpret_cast<const bf16x8*>(xa + 16 * I_DIM);

#pragma unroll
    for (int s = 0; s < NSTEP; ++s) {
        int4 nqa = {}, nqb = {};
        bf16x8 na0 = {}, na1 = {};
        if (s + 1 < NSTEP) {
            const int*            w2 = wq + (s + 1) * 32;
            const unsigned short* x2 = xa + (s + 1) * 32;
            nqa = *reinterpret_cast<const int4*>(w2);
            nqb = *reinterpret_cast<const int4*>(w2 + 4);
            na0 = *reinterpret_cast<const bf16x8*>(x2);
            na1 = *reinterpret_cast<const bf16x8*>(x2 + 16 * I_DIM);
        }
        const bf16x8 bfrag = dequant8(qa, qb, sc[s]);
        acc0 = __builtin_amdgcn_mfma_f32_16x16x32_bf16(a0, bfrag, acc0, 0, 0, 0);
        acc1 = __builtin_amdgcn_mfma_f32_16x16x32_bf16(a1, bfrag, acc1, 0, 0, 0);
        qa = nqa; qb = nqb; a0 = na0; a1 = na1;
    }

    // C/D layout: col = lane&15 (o), row = (lane>>4)*4 + reg (m)  [m89]
#pragma unroll
    for (int r = 0; r < 4; ++r) {
        const int m = lq * 4 + r;
        atomicAdd(&out[m * O_DIM + o_row],        acc0[r]);
        atomicAdd(&out[(m + 16) * O_DIM + o_row], acc1[r]);
    }
}

extern "C" void kernel_launch(void* const* d_in, const int* in_sizes, int n_in,
                              void* d_out, int out_size, void* d_ws, size_t ws_size,
                              hipStream_t stream) {
    const float* x      = (const float*)d_in[0];
    const int*   qw     = (const int*)d_in[1];
    const float* scales = (const float*)d_in[2];
    const float* bias   = (const float*)d_in[3];
    float*       out    = (float*)d_out;
    unsigned short* xbf = (unsigned short*)d_ws;

    // 1) out = bias; x -> bf16 scratch
    hipLaunchKernelGGL(init_kernel, dim3((B_DIM * O_DIM) / 256), dim3(256), 0, stream,
                       x, bias, out, xbf);

    // 2) barrier-free streaming dequant-MFMA GEMM, K-split x8 via atomicAdd
    hipLaunchKernelGGL(gemm_stream_kernel, dim3(O_DIM / 64, NSPLIT), dim3(256), 0, stream,
                       xbf, qw, scales, out);
}